// Round 1
// baseline (495.722 us; speedup 1.0000x reference)
//
#include <hip/hip_runtime.h>
#include <math.h>

typedef unsigned short u16;
typedef unsigned int u32;
typedef short s16x8 __attribute__((ext_vector_type(8)));
typedef float f32x4 __attribute__((ext_vector_type(4)));

#define AS1 __attribute__((address_space(1)))
#define AS3 __attribute__((address_space(3)))

__device__ __forceinline__ float bf2f(u16 u) {
    union { u32 i; float f; } v; v.i = ((u32)u) << 16; return v.f;
}
__device__ __forceinline__ u16 f2bf(float f) {
    union { float f; u32 i; } v; v.f = f;
    u32 r = v.i + 0x7fffu + ((v.i >> 16) & 1u);
    return (u16)(r >> 16);
}
__device__ __forceinline__ void gll16(const u16* g, u16* l) {
    __builtin_amdgcn_global_load_lds((const AS1 u32*)g, (AS3 u32*)l, 16, 0, 0);
}

// ---------------------------------------------------------------------------
// prep: repack weights to B^T bf16 layouts for the MFMA GEMMs
// ---------------------------------------------------------------------------
__global__ void prep_kernel(const float* __restrict__ wd, const float* __restrict__ wqkv,
                            const float* __restrict__ wfc1, const float* __restrict__ wfc2,
                            u16* __restrict__ wdT, u16* __restrict__ wkvT,
                            u16* __restrict__ wf1T, u16* __restrict__ wf2T)
{
    int i = blockIdx.x * 256 + threadIdx.x;
    if (i < 331776) {                       // w_d2T[o][p*192+c] = w_d[o][c][p]
        int o = i / 1728, r = i % 1728;
        int p = r / 192, c = r % 192;
        wdT[i] = f2bf(wd[(o * 192 + c) * 9 + p]);
    }
    if (i < 73728) {                        // rows C..3C of w_qkv (k,v only)
        int o = i / 192, c = i % 192;
        wkvT[i] = f2bf(wqkv[(192 + o) * 192 + c]);
    }
    if (i < 147456) {
        int n = i / 192, c = i % 192;       // w_fc1 (192,768) -> [768][192]
        wf1T[i] = f2bf(wfc1[c * 768 + n]);
        int n2 = i / 768, hh = i % 768;     // w_fc2 (768,192) -> [192][768]
        wf2T[i] = f2bf(wfc2[hh * 192 + n2]);
    }
}

// ---------------------------------------------------------------------------
// LN1: x NCHW fp32 -> xn token-major bf16 [16384][192]
// ---------------------------------------------------------------------------
__global__ __launch_bounds__(256) void ln1_kernel(const float* __restrict__ x,
                                                  const float* __restrict__ g,
                                                  const float* __restrict__ be,
                                                  u16* __restrict__ xn)
{
    __shared__ float red0[256], red1[256];
    __shared__ float mu_s[64], rs_s[64];
    __shared__ u16 tile[64 * 194];          // stride 194 (97 dwords) = conflict-free
    int t = threadIdx.x, tl = t & 63, cg = t >> 6;
    int m0 = blockIdx.x * 64;
    int b = m0 >> 12, hw0 = m0 & 4095;
    const float* xb = x + (size_t)b * 786432 + hw0 + tl;
    float s = 0.f, s2 = 0.f;
    for (int cc = cg; cc < 192; cc += 4) { float v = xb[cc * 4096]; s += v; s2 += v * v; }
    red0[t] = s; red1[t] = s2;
    __syncthreads();
    if (t < 64) {
        float a = red0[t] + red0[64 + t] + red0[128 + t] + red0[192 + t];
        float q = red1[t] + red1[64 + t] + red1[128 + t] + red1[192 + t];
        float mu = a * (1.f / 192.f);
        float var = q * (1.f / 192.f) - mu * mu;
        mu_s[t] = mu; rs_s[t] = rsqrtf(var + 1e-5f);
    }
    __syncthreads();
    float mu = mu_s[tl], rs = rs_s[tl];
    for (int cc = cg; cc < 192; cc += 4) {
        float v = (xb[cc * 4096] - mu) * rs * g[cc] + be[cc];
        tile[tl * 194 + cc] = f2bf(v);
    }
    __syncthreads();
    u32* dst = (u32*)(xn + (size_t)m0 * 192);
    for (int i = t; i < 64 * 96; i += 256) {
        int r = i / 96, c2 = i % 96;
        dst[i] = *(const u32*)&tile[r * 194 + c2 * 2];
    }
}

// ---------------------------------------------------------------------------
// offset conv: 3x3, pad 1, 18 out channels; off token-major fp32 [16384][18]
// one block per (b,h) row; LDS holds 3 input rows with w-halo.
// weights stream through the scalar pipe (wave-uniform o).
// ---------------------------------------------------------------------------
__global__ __launch_bounds__(256) void offconv_kernel(const u16* __restrict__ xn,
                                                      const float* __restrict__ wp,
                                                      const float* __restrict__ bp,
                                                      float* __restrict__ off)
{
    __shared__ u16 tile[3 * 66 * 194];      // [row][w+halo][c], c-stride 194
    int bh = blockIdx.x;
    int b = bh >> 6, h = bh & 63;
    int t = threadIdx.x;
    for (int i = t; i < 3 * 66 * 96; i += 256) {
        int ri = i / (66 * 96);
        int rem = i - ri * 66 * 96;
        int wi = rem / 96, cp = rem % 96;
        int hr = h - 1 + ri, wr = wi - 1;
        u32 v = 0;
        if (hr >= 0 && hr < 64 && wr >= 0 && wr < 64)
            v = *(const u32*)(xn + ((size_t)(b * 4096 + hr * 64 + wr)) * 192 + cp * 2);
        *(u32*)&tile[(ri * 66 + wi) * 194 + cp * 2] = v;
    }
    __syncthreads();
    int w = t & 63;
    int og = __builtin_amdgcn_readfirstlane(t >> 6);     // wave-uniform -> scalar weights
    const int ostart4[4] = {0, 5, 9, 13};                // overlaps write same value (benign)
    int os = ostart4[og];
    float acc[5];
#pragma unroll
    for (int u = 0; u < 5; u++) acc[u] = bp[os + u];
    for (int c = 0; c < 192; c++) {
#pragma unroll
        for (int di = 0; di < 3; di++)
#pragma unroll
            for (int dj = 0; dj < 3; dj++) {
                float v = bf2f(tile[(di * 66 + (w + dj)) * 194 + c]);
                int ij = di * 3 + dj;
#pragma unroll
                for (int u = 0; u < 5; u++)
                    acc[u] += v * wp[((os + u) * 192 + c) * 9 + ij];
            }
    }
    float* orow = off + ((size_t)(b * 4096 + h * 64 + w)) * 18;
#pragma unroll
    for (int u = 0; u < 5; u++) orow[os + u] = acc[u];
}

// ---------------------------------------------------------------------------
// bilinear gather: build deform im2col A [16384][1728] bf16, k = p*192 + c
// ---------------------------------------------------------------------------
__global__ __launch_bounds__(192) void gather_kernel(const u16* __restrict__ xn,
                                                     const float* __restrict__ off,
                                                     u16* __restrict__ Adef)
{
    __shared__ int sidx[9][4];
    __shared__ float swt[9][4];
    int m = blockIdx.x;
    int b = m >> 12, hw = m & 4095;
    int h = hw >> 6, w = hw & 63;
    int t = threadIdx.x;
    if (t < 9) {
        int p = t;
        float ox = off[(size_t)m * 18 + p];
        float oy = off[(size_t)m * 18 + 9 + p];
        float px = ox + (float)(h + 1) + (float)(p / 3 - 1);
        float py = oy + (float)(w + 1) + (float)(p % 3 - 1);
        float fx = floorf(px), fy = floorf(py);
        float qlx = fminf(fmaxf(fx, 0.f), 65.f);
        float qly = fminf(fmaxf(fy, 0.f), 65.f);
        float qrx = fminf(fmaxf(fx + 1.f, 0.f), 65.f);
        float qry = fminf(fmaxf(fy + 1.f, 0.f), 65.f);
        float pxc = fminf(fmaxf(px, 0.f), 65.f);
        float pyc = fminf(fmaxf(py, 0.f), 65.f);
        float gxl = 1.f + (qlx - pxc), gxr = 1.f - (qrx - pxc);
        float gyl = 1.f + (qly - pyc), gyr = 1.f - (qry - pyc);
        int xl = (int)qlx, xr = (int)qrx, yl = (int)qly, yr = (int)qry;
        int ib;
        ib = (xl >= 1 && xl <= 64 && yl >= 1 && yl <= 64) ? (b * 4096 + (xl - 1) * 64 + (yl - 1)) * 192 : -1;
        sidx[p][0] = ib; swt[p][0] = gxl * gyl;
        ib = (xr >= 1 && xr <= 64 && yr >= 1 && yr <= 64) ? (b * 4096 + (xr - 1) * 64 + (yr - 1)) * 192 : -1;
        sidx[p][1] = ib; swt[p][1] = gxr * gyr;
        ib = (xl >= 1 && xl <= 64 && yr >= 1 && yr <= 64) ? (b * 4096 + (xl - 1) * 64 + (yr - 1)) * 192 : -1;
        sidx[p][2] = ib; swt[p][2] = gxl * gyr;
        ib = (xr >= 1 && xr <= 64 && yl >= 1 && yl <= 64) ? (b * 4096 + (xr - 1) * 64 + (yl - 1)) * 192 : -1;
        sidx[p][3] = ib; swt[p][3] = gxr * gyl;
    }
    __syncthreads();
    u16* arow = Adef + (size_t)m * 1728;
    for (int p = 0; p < 9; p++) {
        float v = 0.f;
#pragma unroll
        for (int k = 0; k < 4; k++) {
            int id = sidx[p][k];                 // wave-uniform
            if (id >= 0) v += swt[p][k] * bf2f(xn[id + t]);
        }
        arow[p * 192 + t] = f2bf(v);
    }
}

// ---------------------------------------------------------------------------
// templated bf16 MFMA GEMM: C[M,N] = A[M,K] * B^T[N,K], m97-style staging
// EP: 0 = bf16 store, 1 = +x residual (NCHW) -> fp32, 2 = +bias,gelu -> bf16,
//     3 = +bias -> fp32
// ---------------------------------------------------------------------------
template<int BM, int BN, int WM, int WN, int EP>
__global__ __launch_bounds__((BM / WM) * (BN / WN) * 64)
void gemm_bt(const u16* __restrict__ A, int lda,
             const u16* __restrict__ B, int ldb, int bstride,
             void* __restrict__ out, int ldc,
             const float* __restrict__ ex1, int K)
{
    constexpr int BK = 32;
    constexpr int WAVES_M = BM / WM, WAVES_N = BN / WN, NW = WAVES_M * WAVES_N;
    constexpr int TM = WM / 16, TN = WN / 16;
    constexpr int NLA = BM / 16, NLB = BN / 16;   // 1KB global_load_lds chunks
    __shared__ u16 As[BM * BK];
    __shared__ u16 Bs[BN * BK];
    int tid = threadIdx.x;
    int lane = tid & 63, wv = tid >> 6;
    int wm = wv % WAVES_M, wn = wv / WAVES_M;
    int m0 = blockIdx.x * BM, n0 = blockIdx.y * BN;
    const u16* Bp = B + (size_t)(m0 >> 12) * bstride;
    f32x4 acc[TM][TN];
#pragma unroll
    for (int i = 0; i < TM; i++)
#pragma unroll
        for (int j = 0; j < TN; j++) {
            acc[i][j][0] = 0.f; acc[i][j][1] = 0.f; acc[i][j][2] = 0.f; acc[i][j][3] = 0.f;
        }
    int arow_l = lane >> 2;
    int acol_l = (lane & 3) * 8;
    for (int k0 = 0; k0 < K; k0 += BK) {
#pragma unroll 1
        for (int j = wv; j < NLA + NLB; j += NW) {
            if (j < NLA) {
                int row = j * 16 + arow_l;
                gll16(A + (size_t)(m0 + row) * lda + k0 + acol_l, As + j * 512);
            } else {
                int row = (j - NLA) * 16 + arow_l;
                gll16(Bp + (size_t)(n0 + row) * ldb + k0 + acol_l, Bs + (j - NLA) * 512);
            }
        }
        asm volatile("s_waitcnt vmcnt(0)" ::: "memory");
        __syncthreads();
        s16x8 af[TM], bfr[TN];
#pragma unroll
        for (int i = 0; i < TM; i++)
            af[i] = *(const s16x8*)&As[(wm * WM + i * 16 + (lane & 15)) * BK + (lane >> 4) * 8];
#pragma unroll
        for (int j = 0; j < TN; j++)
            bfr[j] = *(const s16x8*)&Bs[(wn * WN + j * 16 + (lane & 15)) * BK + (lane >> 4) * 8];
#pragma unroll
        for (int i = 0; i < TM; i++)
#pragma unroll
            for (int j = 0; j < TN; j++)
                acc[i][j] = __builtin_amdgcn_mfma_f32_16x16x32_bf16(af[i], bfr[j], acc[i][j], 0, 0, 0);
        __syncthreads();
    }
    // epilogue: C row = (lane>>4)*4 + r, col = lane&15
    int col = lane & 15;
#pragma unroll
    for (int i = 0; i < TM; i++)
#pragma unroll
        for (int j = 0; j < TN; j++) {
            int mm = m0 + wm * WM + i * 16 + (lane >> 4) * 4;
            int nn = n0 + wn * WN + j * 16 + col;
            if (EP == 0) {
                u16* o = (u16*)out;
#pragma unroll
                for (int r = 0; r < 4; r++) o[(size_t)(mm + r) * ldc + nn] = f2bf(acc[i][j][r]);
            } else if (EP == 1) {
                float* o = (float*)out;
                const float* xr = ex1 + (size_t)(mm >> 12) * 786432 + (size_t)nn * 4096 + (mm & 4095);
#pragma unroll
                for (int r = 0; r < 4; r++) o[(size_t)(mm + r) * ldc + nn] = acc[i][j][r] + xr[r];
            } else if (EP == 2) {
                u16* o = (u16*)out;
                float bb = ex1[nn];
#pragma unroll
                for (int r = 0; r < 4; r++) {
                    float v = acc[i][j][r] + bb;
                    o[(size_t)(mm + r) * ldc + nn] = f2bf(0.5f * v * (1.f + erff(v * 0.70710678118654752f)));
                }
            } else {
                float* o = (float*)out;
                float bb = ex1[nn];
#pragma unroll
                for (int r = 0; r < 4; r++) o[(size_t)(mm + r) * ldc + nn] = acc[i][j][r] + bb;
            }
        }
}

// ---------------------------------------------------------------------------
// l2norm sums: norm2[b][col] = sum_n kv[n][col]^2   (col 0..383 = k then v)
// ---------------------------------------------------------------------------
__global__ __launch_bounds__(384) void norm_kernel(const u16* __restrict__ kv,
                                                   float* __restrict__ norm2)
{
    int b = blockIdx.y, ch = blockIdx.x;
    int t = threadIdx.x;
    const u16* base = kv + ((size_t)(b * 4096 + ch * 128)) * 384 + t;
    float s = 0.f;
    for (int r = 0; r < 128; r++) { float v = bf2f(base[(size_t)r * 384]); s += v * v; }
    atomicAdd(&norm2[b * 384 + t], s);
}

// ---------------------------------------------------------------------------
// attention logits partials: raw[b,h,c,d] += sum_{r in chunk} q[r][c]*k[r][d]
// one wave per (chunk of 64 tokens, h, b); 4x4 register tile per thread
// ---------------------------------------------------------------------------
__global__ __launch_bounds__(64) void attnp_kernel(const u16* __restrict__ qt,
                                                   const u16* __restrict__ kvt,
                                                   float* __restrict__ raw)
{
    __shared__ float qT[32 * 69];
    __shared__ float kT[32 * 69];
    int ch = blockIdx.x, h = blockIdx.y, b = blockIdx.z;
    int t = threadIdx.x;
    size_t base = (size_t)(b * 4096 + ch * 64);
    for (int e = t; e < 2048; e += 64) {
        int r = e >> 5, c = e & 31;
        qT[c * 69 + r] = bf2f(qt[(base + r) * 192 + h * 32 + c]);
        kT[c * 69 + r] = bf2f(kvt[(base + r) * 384 + h * 32 + c]);
    }
    __syncthreads();
    int tc = t >> 3, td = t & 7;
    int c0 = tc * 4, d0 = td * 4;
    float acc[4][4] = {};
    for (int r = 0; r < 64; r++) {
        float qv[4], kv4[4];
#pragma unroll
        for (int u = 0; u < 4; u++) { qv[u] = qT[(c0 + u) * 69 + r]; kv4[u] = kT[(d0 + u) * 69 + r]; }
#pragma unroll
        for (int u = 0; u < 4; u++)
#pragma unroll
            for (int v = 0; v < 4; v++) acc[u][v] += qv[u] * kv4[v];
    }
    float* dst = raw + ((size_t)(b * 6 + h)) * 1024;
#pragma unroll
    for (int u = 0; u < 4; u++)
#pragma unroll
        for (int v = 0; v < 4; v++)
            atomicAdd(&dst[(c0 + u) * 32 + d0 + v], acc[u][v]);
}

// ---------------------------------------------------------------------------
// softmax over d with k-norm + temperature folded in; v-norm folded into out
// ---------------------------------------------------------------------------
__global__ __launch_bounds__(1024) void softmax_kernel(const float* __restrict__ raw,
                                                       const float* __restrict__ norm2,
                                                       const float* __restrict__ temp,
                                                       float* __restrict__ att2)
{
    int h = blockIdx.x, b = blockIdx.y;
    int t = threadIdx.x;
    int c = t >> 5, d = t & 31;
    __shared__ float invk[32], invv[32];
    if (t < 32)       invk[t] = 1.f / fmaxf(sqrtf(norm2[b * 384 + h * 32 + t]), 1e-12f);
    else if (t < 64)  invv[t - 32] = 1.f / fmaxf(sqrtf(norm2[b * 384 + 192 + h * 32 + (t - 32)]), 1e-12f);
    __syncthreads();
    float T = temp[h];
    float v = raw[((size_t)(b * 6 + h) * 32 + c) * 32 + d] * invk[d] * T;
    float mx = v;
    for (int s = 16; s > 0; s >>= 1) mx = fmaxf(mx, __shfl_xor(mx, s, 32));
    float e = expf(v - mx);
    float sm = e;
    for (int s = 16; s > 0; s >>= 1) sm += __shfl_xor(sm, s, 32);
    att2[((size_t)(b * 6 + h) * 32 + c) * 32 + d] = (e / sm) * invv[d];
}

// ---------------------------------------------------------------------------
// M_b[b][o2][h*32+d] = sum_c w_proj[o2][h*32+c] * att2[b][h][c][d]  (bf16)
// ---------------------------------------------------------------------------
__global__ __launch_bounds__(192) void mb_kernel(const float* __restrict__ wproj,
                                                 const float* __restrict__ att2,
                                                 u16* __restrict__ Mb)
{
    int o2 = blockIdx.x, b = blockIdx.y, t = threadIdx.x;
    int h = t >> 5, d = t & 31;
    float s = 0.f;
#pragma unroll
    for (int c = 0; c < 32; c++)
        s += wproj[o2 * 192 + h * 32 + c] * att2[((size_t)(b * 6 + h) * 32 + c) * 32 + d];
    Mb[((size_t)b * 192 + o2) * 192 + t] = f2bf(s);
}

// ---------------------------------------------------------------------------
// LN2: xs2 fp32 token-major -> h1 bf16 token-major; one wave per token
// ---------------------------------------------------------------------------
__global__ __launch_bounds__(256) void ln2_kernel(const float* __restrict__ xs2,
                                                  const float* __restrict__ g,
                                                  const float* __restrict__ be,
                                                  u16* __restrict__ h1)
{
    int t = threadIdx.x;
    int wv = t >> 6, l = t & 63;
    size_t m = (size_t)blockIdx.x * 4 + wv;
    const float* row = xs2 + m * 192;
    float v0 = row[l], v1 = row[l + 64], v2 = row[l + 128];
    float s = v0 + v1 + v2, s2 = v0 * v0 + v1 * v1 + v2 * v2;
    for (int sh = 32; sh > 0; sh >>= 1) { s += __shfl_xor(s, sh); s2 += __shfl_xor(s2, sh); }
    float mu = s * (1.f / 192.f);
    float var = s2 * (1.f / 192.f) - mu * mu;
    float rs = rsqrtf(var + 1e-5f);
    u16* o = h1 + m * 192;
    o[l]       = f2bf((v0 - mu) * rs * g[l]       + be[l]);
    o[l + 64]  = f2bf((v1 - mu) * rs * g[l + 64]  + be[l + 64]);
    o[l + 128] = f2bf((v2 - mu) * rs * g[l + 128] + be[l + 128]);
}

// ---------------------------------------------------------------------------
// final: out[b][c][hw] = xs2[m][c] + m2[m][c]  (LDS transpose, coalesced)
// ---------------------------------------------------------------------------
__global__ __launch_bounds__(256) void final_kernel(const float* __restrict__ xs2,
                                                    const float* __restrict__ m2,
                                                    float* __restrict__ out)
{
    __shared__ float tile[192 * 65];
    int blk = blockIdx.x;
    int b = blk >> 6, hw0 = (blk & 63) * 64;
    int t = threadIdx.x;
    size_t mbase = ((size_t)b * 4096 + hw0) * 192;
    for (int i = t; i < 64 * 192; i += 256) {
        int r = i / 192, c = i % 192;
        tile[c * 65 + r] = xs2[mbase + i] + m2[mbase + i];
    }
    __syncthreads();
    for (int i = t; i < 64 * 192; i += 256) {
        int c = i / 64, r = i % 64;
        out[(size_t)b * 786432 + (size_t)c * 4096 + hw0 + r] = tile[c * 65 + r];
    }
}

// ---------------------------------------------------------------------------
extern "C" void kernel_launch(void* const* d_in, const int* in_sizes, int n_in,
                              void* d_out, int out_size, void* d_ws, size_t ws_size,
                              hipStream_t stream)
{
    const float* x      = (const float*)d_in[0];
    const float* gamma1 = (const float*)d_in[1];
    const float* beta1  = (const float*)d_in[2];
    const float* gamma2 = (const float*)d_in[3];
    const float* beta2  = (const float*)d_in[4];
    const float* temp   = (const float*)d_in[5];
    const float* w_qkv  = (const float*)d_in[6];
    const float* w_proj = (const float*)d_in[7];
    const float* w_p    = (const float*)d_in[8];
    const float* b_p    = (const float*)d_in[9];
    const float* w_d    = (const float*)d_in[10];
    const float* w_fc1  = (const float*)d_in[11];
    const float* b_fc1  = (const float*)d_in[12];
    const float* w_fc2  = (const float*)d_in[13];
    const float* b_fc2  = (const float*)d_in[14];
    float* out = (float*)d_out;
    char* ws = (char*)d_ws;

    u16*   xn    = (u16*)(ws + 0);                     // 6.29 MB (aliased: h1)
    float* off   = (float*)(ws + 6291456);             // 1.18 MB
    u16*   adef  = (u16*)(ws + 7471104);               // 56.6 MB (aliased: m1, m2)
    u16*   m1    = adef;                               // 25.2 MB
    float* m2    = (float*)(ws + 7471104 + 25165824);  // 12.6 MB
    u16*   qt    = (u16*)(ws + 64094208);              // 6.29 MB
    u16*   kvt   = (u16*)(ws + 70385664);              // 12.6 MB
    float* norm2 = (float*)(ws + 82968576);            // 6 KB
    float* araw  = (float*)(ws + 82974720);            // 96 KB
    float* att2  = (float*)(ws + 83073024);            // 96 KB
    u16*   Mb    = (u16*)(ws + 83171328);              // 144 KB
    float* xs2   = (float*)(ws + 83318784);            // 12.6 MB
    u16*   h1    = xn;
    u16*   wdT   = (u16*)(ws + 95901696);
    u16*   wkvT  = (u16*)(ws + 96565248);
    u16*   wf1T  = (u16*)(ws + 96712704);
    u16*   wf2T  = (u16*)(ws + 97007616);              // end 97302528 B

    hipMemsetAsync(norm2, 0, 6144 + 98304, stream);
    prep_kernel<<<1296, 256, 0, stream>>>(w_d, w_qkv, w_fc1, w_fc2, wdT, wkvT, wf1T, wf2T);
    ln1_kernel<<<256, 256, 0, stream>>>(x, gamma1, beta1, xn);
    offconv_kernel<<<256, 256, 0, stream>>>(xn, w_p, b_p, off);
    gather_kernel<<<16384, 192, 0, stream>>>(xn, off, adef);
    // deform output conv as GEMM: M=16384 K=1728 N=192
    gemm_bt<32, 192, 32, 96, 0><<<dim3(512, 1), 128, 0, stream>>>(adef, 1728, wdT, 1728, 0, qt, 192, nullptr, 1728);
    // k,v projection: M=16384 K=192 N=384
    gemm_bt<128, 128, 64, 64, 0><<<dim3(128, 3), 256, 0, stream>>>(xn, 192, wkvT, 192, 0, kvt, 384, nullptr, 192);
    norm_kernel<<<dim3(32, 4), 384, 0, stream>>>(kvt, norm2);
    attnp_kernel<<<dim3(64, 6, 4), 64, 0, stream>>>(qt, kvt, araw);
    softmax_kernel<<<dim3(6, 4), 1024, 0, stream>>>(araw, norm2, temp, att2);
    mb_kernel<<<dim3(192, 4), 192, 0, stream>>>(w_proj, att2, Mb);
    // fused attn-apply+proj GEMM on raw v, + x residual -> xs2 fp32
    gemm_bt<32, 192, 32, 96, 1><<<dim3(512, 1), 128, 0, stream>>>(kvt + 192, 384, Mb, 192, 192 * 192, xs2, 192, x, 192);
    ln2_kernel<<<4096, 256, 0, stream>>>(xs2, gamma2, beta2, h1);
    // fc1 + gelu: M=16384 K=192 N=768
    gemm_bt<128, 128, 64, 64, 2><<<dim3(128, 6), 256, 0, stream>>>(h1, 192, wf1T, 192, 0, m1, 768, b_fc1, 192);
    // fc2 + bias: M=16384 K=768 N=192
    gemm_bt<32, 192, 32, 96, 3><<<dim3(512, 1), 128, 0, stream>>>(m1, 768, wf2T, 768, 0, m2, 192, b_fc2, 768);
    final_kernel<<<256, 256, 0, stream>>>(xs2, m2, out);
}

// Round 2
// 366.431 us; speedup vs baseline: 1.3528x; 1.3528x over previous
//
#include <hip/hip_runtime.h>
#include <math.h>

typedef unsigned short u16;
typedef unsigned int u32;
typedef short s16x8 __attribute__((ext_vector_type(8)));
typedef float f32x4 __attribute__((ext_vector_type(4)));

#define AS1 __attribute__((address_space(1)))
#define AS3 __attribute__((address_space(3)))

__device__ __forceinline__ float bf2f(u16 u) {
    union { u32 i; float f; } v; v.i = ((u32)u) << 16; return v.f;
}
__device__ __forceinline__ u16 f2bf(float f) {
    union { float f; u32 i; } v; v.f = f;
    u32 r = v.i + 0x7fffu + ((v.i >> 16) & 1u);
    return (u16)(r >> 16);
}
__device__ __forceinline__ void gll16(const u16* g, u16* l) {
    __builtin_amdgcn_global_load_lds((const AS1 u32*)g, (AS3 u32*)l, 16, 0, 0);
}

// ---------------------------------------------------------------------------
// prep: repack weights to B^T bf16 layouts for the MFMA GEMMs
// ---------------------------------------------------------------------------
__global__ void prep_kernel(const float* __restrict__ wd, const float* __restrict__ wqkv,
                            const float* __restrict__ wfc1, const float* __restrict__ wfc2,
                            const float* __restrict__ wp,
                            u16* __restrict__ wdT, u16* __restrict__ wkvT,
                            u16* __restrict__ wf1T, u16* __restrict__ wf2T,
                            u16* __restrict__ wpT)
{
    int i = blockIdx.x * 256 + threadIdx.x;
    if (i < 331776) {                       // w_dT[o][p*192+c] = w_d[o][c][p]
        int o = i / 1728, r = i % 1728;
        int p = r / 192, c = r % 192;
        wdT[i] = f2bf(wd[(o * 192 + c) * 9 + p]);
    }
    if (i < 73728) {                        // rows C..3C of w_qkv (k,v only)
        int o = i / 192, c = i % 192;
        wkvT[i] = f2bf(wqkv[(192 + o) * 192 + c]);
    }
    if (i < 147456) {
        int n = i / 192, c = i % 192;       // w_fc1 (192,768) -> [768][192]
        wf1T[i] = f2bf(wfc1[c * 768 + n]);
        int n2 = i / 768, hh = i % 768;     // w_fc2 (768,192) -> [192][768]
        wf2T[i] = f2bf(wfc2[hh * 192 + n2]);
    }
    if (i < 31104) {                        // w_pT[n][p*192+c] = w_p[n][c][p], pad to 32 rows
        int n = i / 1728, r = i % 1728;
        int p = r / 192, c = r % 192;
        wpT[i] = f2bf(wp[(n * 192 + c) * 9 + p]);
    } else if (i < 55296) {
        wpT[i] = 0;
    }
}

// ---------------------------------------------------------------------------
// LN1: x NCHW fp32 -> xn token-major bf16 [16384][192]
// ---------------------------------------------------------------------------
__global__ __launch_bounds__(256) void ln1_kernel(const float* __restrict__ x,
                                                  const float* __restrict__ g,
                                                  const float* __restrict__ be,
                                                  u16* __restrict__ xn)
{
    __shared__ float red0[256], red1[256];
    __shared__ float mu_s[64], rs_s[64];
    __shared__ u16 tile[64 * 194];          // stride 194 (97 dwords) = conflict-free
    int t = threadIdx.x, tl = t & 63, cg = t >> 6;
    int m0 = blockIdx.x * 64;
    int b = m0 >> 12, hw0 = m0 & 4095;
    const float* xb = x + (size_t)b * 786432 + hw0 + tl;
    float s = 0.f, s2 = 0.f;
    for (int cc = cg; cc < 192; cc += 4) { float v = xb[cc * 4096]; s += v; s2 += v * v; }
    red0[t] = s; red1[t] = s2;
    __syncthreads();
    if (t < 64) {
        float a = red0[t] + red0[64 + t] + red0[128 + t] + red0[192 + t];
        float q = red1[t] + red1[64 + t] + red1[128 + t] + red1[192 + t];
        float mu = a * (1.f / 192.f);
        float var = q * (1.f / 192.f) - mu * mu;
        mu_s[t] = mu; rs_s[t] = rsqrtf(var + 1e-5f);
    }
    __syncthreads();
    float mu = mu_s[tl], rs = rs_s[tl];
    for (int cc = cg; cc < 192; cc += 4) {
        float v = (xb[cc * 4096] - mu) * rs * g[cc] + be[cc];
        tile[tl * 194 + cc] = f2bf(v);
    }
    __syncthreads();
    u32* dst = (u32*)(xn + (size_t)m0 * 192);
    for (int i = t; i < 64 * 96; i += 256) {
        int r = i / 96, c2 = i % 96;
        dst[i] = *(const u32*)&tile[r * 194 + c2 * 2];
    }
}

// ---------------------------------------------------------------------------
// offset conv as direct MFMA conv: one block per (b,h) row, BM=64 (w axis),
// N=32 (18 padded), K = 9 taps x 192 ch. A staged per tap from token-major xn
// with predicated loads (zero padding); B = wpT tap slice.
// ---------------------------------------------------------------------------
__global__ __launch_bounds__(256) void offconv_kernel(const u16* __restrict__ xn,
                                                      const u16* __restrict__ wpT,
                                                      const float* __restrict__ bp,
                                                      float* __restrict__ off)
{
    __shared__ u16 As[64 * 200];            // stride 200: 100 dw, rows rotate 4 banks
    __shared__ u16 Bs[32 * 200];
    int bh = blockIdx.x;
    int b = bh >> 6, h = bh & 63;
    int t = threadIdx.x;
    int lane = t & 63, wv = t >> 6;
    f32x4 acc[2];
#pragma unroll
    for (int j = 0; j < 2; j++) { acc[j][0] = 0.f; acc[j][1] = 0.f; acc[j][2] = 0.f; acc[j][3] = 0.f; }
    int r = t >> 2, cq = (t & 3) * 48;      // 4 threads per A row, 48 ch each
    for (int p = 0; p < 9; p++) {
        int dh = p / 3 - 1, dw = p % 3 - 1;
        int hr = h + dh, wr = r + dw;
        bool valid = (hr >= 0) && (hr < 64) && (wr >= 0) && (wr < 64);
        const u16* src = xn + ((size_t)(b * 4096 + hr * 64 + wr)) * 192 + cq;
#pragma unroll
        for (int j = 0; j < 6; j++) {
            s16x8 v = {0, 0, 0, 0, 0, 0, 0, 0};
            if (valid) v = *(const s16x8*)(src + j * 8);
            *(s16x8*)&As[r * 200 + cq + j * 8] = v;
        }
#pragma unroll
        for (int i = 0; i < 3; i++) {
            int q = t + i * 256;
            int n = q / 24, c8 = q % 24;
            *(s16x8*)&Bs[n * 200 + c8 * 8] =
                *(const s16x8*)(wpT + n * 1728 + p * 192 + c8 * 8);
        }
        __syncthreads();
#pragma unroll
        for (int kc = 0; kc < 6; kc++) {
            s16x8 af = *(const s16x8*)&As[(wv * 16 + (lane & 15)) * 200 + kc * 32 + (lane >> 4) * 8];
            s16x8 b0 = *(const s16x8*)&Bs[(lane & 15) * 200 + kc * 32 + (lane >> 4) * 8];
            s16x8 b1 = *(const s16x8*)&Bs[(16 + (lane & 15)) * 200 + kc * 32 + (lane >> 4) * 8];
            acc[0] = __builtin_amdgcn_mfma_f32_16x16x32_bf16(af, b0, acc[0], 0, 0, 0);
            acc[1] = __builtin_amdgcn_mfma_f32_16x16x32_bf16(af, b1, acc[1], 0, 0, 0);
        }
        __syncthreads();
    }
    int col = lane & 15;
    int wbase = wv * 16 + (lane >> 4) * 4;
#pragma unroll
    for (int j = 0; j < 2; j++) {
        int n = j * 16 + col;
        if (n < 18) {
            float bb = bp[n];
#pragma unroll
            for (int rr = 0; rr < 4; rr++) {
                int w = wbase + rr;
                off[((size_t)(b * 4096 + h * 64 + w)) * 18 + n] = acc[j][rr] + bb;
            }
        }
    }
}

// ---------------------------------------------------------------------------
// bilinear gather: build deform im2col A [16384][1728] bf16, k = p*192 + c
// ---------------------------------------------------------------------------
__global__ __launch_bounds__(192) void gather_kernel(const u16* __restrict__ xn,
                                                     const float* __restrict__ off,
                                                     u16* __restrict__ Adef)
{
    __shared__ int sidx[9][4];
    __shared__ float swt[9][4];
    int m = blockIdx.x;
    int b = m >> 12, hw = m & 4095;
    int h = hw >> 6, w = hw & 63;
    int t = threadIdx.x;
    if (t < 9) {
        int p = t;
        float ox = off[(size_t)m * 18 + p];
        float oy = off[(size_t)m * 18 + 9 + p];
        float px = ox + (float)(h + 1) + (float)(p / 3 - 1);
        float py = oy + (float)(w + 1) + (float)(p % 3 - 1);
        float fx = floorf(px), fy = floorf(py);
        float qlx = fminf(fmaxf(fx, 0.f), 65.f);
        float qly = fminf(fmaxf(fy, 0.f), 65.f);
        float qrx = fminf(fmaxf(fx + 1.f, 0.f), 65.f);
        float qry = fminf(fmaxf(fy + 1.f, 0.f), 65.f);
        float pxc = fminf(fmaxf(px, 0.f), 65.f);
        float pyc = fminf(fmaxf(py, 0.f), 65.f);
        float gxl = 1.f + (qlx - pxc), gxr = 1.f - (qrx - pxc);
        float gyl = 1.f + (qly - pyc), gyr = 1.f - (qry - pyc);
        int xl = (int)qlx, xr = (int)qrx, yl = (int)qly, yr = (int)qry;
        int ib;
        ib = (xl >= 1 && xl <= 64 && yl >= 1 && yl <= 64) ? (b * 4096 + (xl - 1) * 64 + (yl - 1)) * 192 : -1;
        sidx[p][0] = ib; swt[p][0] = gxl * gyl;
        ib = (xr >= 1 && xr <= 64 && yr >= 1 && yr <= 64) ? (b * 4096 + (xr - 1) * 64 + (yr - 1)) * 192 : -1;
        sidx[p][1] = ib; swt[p][1] = gxr * gyr;
        ib = (xl >= 1 && xl <= 64 && yr >= 1 && yr <= 64) ? (b * 4096 + (xl - 1) * 64 + (yr - 1)) * 192 : -1;
        sidx[p][2] = ib; swt[p][2] = gxl * gyr;
        ib = (xr >= 1 && xr <= 64 && yl >= 1 && yl <= 64) ? (b * 4096 + (xr - 1) * 64 + (yl - 1)) * 192 : -1;
        sidx[p][3] = ib; swt[p][3] = gxr * gyl;
    }
    __syncthreads();
    u16* arow = Adef + (size_t)m * 1728;
    for (int p = 0; p < 9; p++) {
        float v = 0.f;
#pragma unroll
        for (int k = 0; k < 4; k++) {
            int id = sidx[p][k];                 // wave-uniform
            if (id >= 0) v += swt[p][k] * bf2f(xn[id + t]);
        }
        arow[p * 192 + t] = f2bf(v);
    }
}

// ---------------------------------------------------------------------------
// templated bf16 MFMA GEMM: C[M,N] = A[M,K] * B^T[N,K], m97-style staging
// EP: 0 = bf16 store, 1 = +x residual (NCHW) -> fp32, 2 = +bias,gelu -> bf16,
//     3 = +bias -> fp32
// ---------------------------------------------------------------------------
template<int BM, int BN, int WM, int WN, int EP>
__global__ __launch_bounds__((BM / WM) * (BN / WN) * 64)
void gemm_bt(const u16* __restrict__ A, int lda,
             const u16* __restrict__ B, int ldb, int bstride,
             void* __restrict__ out, int ldc,
             const float* __restrict__ ex1, int K)
{
    constexpr int BK = 32;
    constexpr int WAVES_M = BM / WM, WAVES_N = BN / WN, NW = WAVES_M * WAVES_N;
    constexpr int TM = WM / 16, TN = WN / 16;
    constexpr int NLA = BM / 16, NLB = BN / 16;   // 1KB global_load_lds chunks
    __shared__ u16 As[BM * BK];
    __shared__ u16 Bs[BN * BK];
    int tid = threadIdx.x;
    int lane = tid & 63, wv = tid >> 6;
    int wm = wv % WAVES_M, wn = wv / WAVES_M;
    int m0 = blockIdx.x * BM, n0 = blockIdx.y * BN;
    const u16* Bp = B + (size_t)(m0 >> 12) * bstride;
    f32x4 acc[TM][TN];
#pragma unroll
    for (int i = 0; i < TM; i++)
#pragma unroll
        for (int j = 0; j < TN; j++) {
            acc[i][j][0] = 0.f; acc[i][j][1] = 0.f; acc[i][j][2] = 0.f; acc[i][j][3] = 0.f;
        }
    int arow_l = lane >> 2;
    int acol_l = (lane & 3) * 8;
    for (int k0 = 0; k0 < K; k0 += BK) {
#pragma unroll 1
        for (int j = wv; j < NLA + NLB; j += NW) {
            if (j < NLA) {
                int row = j * 16 + arow_l;
                gll16(A + (size_t)(m0 + row) * lda + k0 + acol_l, As + j * 512);
            } else {
                int row = (j - NLA) * 16 + arow_l;
                gll16(Bp + (size_t)(n0 + row) * ldb + k0 + acol_l, Bs + (j - NLA) * 512);
            }
        }
        asm volatile("s_waitcnt vmcnt(0)" ::: "memory");
        __syncthreads();
        s16x8 af[TM], bfr[TN];
#pragma unroll
        for (int i = 0; i < TM; i++)
            af[i] = *(const s16x8*)&As[(wm * WM + i * 16 + (lane & 15)) * BK + (lane >> 4) * 8];
#pragma unroll
        for (int j = 0; j < TN; j++)
            bfr[j] = *(const s16x8*)&Bs[(wn * WN + j * 16 + (lane & 15)) * BK + (lane >> 4) * 8];
#pragma unroll
        for (int i = 0; i < TM; i++)
#pragma unroll
            for (int j = 0; j < TN; j++)
                acc[i][j] = __builtin_amdgcn_mfma_f32_16x16x32_bf16(af[i], bfr[j], acc[i][j], 0, 0, 0);
        __syncthreads();
    }
    // epilogue: C row = (lane>>4)*4 + r, col = lane&15
    int col = lane & 15;
#pragma unroll
    for (int i = 0; i < TM; i++)
#pragma unroll
        for (int j = 0; j < TN; j++) {
            int mm = m0 + wm * WM + i * 16 + (lane >> 4) * 4;
            int nn = n0 + wn * WN + j * 16 + col;
            if (EP == 0) {
                u16* o = (u16*)out;
#pragma unroll
                for (int r = 0; r < 4; r++) o[(size_t)(mm + r) * ldc + nn] = f2bf(acc[i][j][r]);
            } else if (EP == 1) {
                float* o = (float*)out;
                const float* xr = ex1 + (size_t)(mm >> 12) * 786432 + (size_t)nn * 4096 + (mm & 4095);
#pragma unroll
                for (int r = 0; r < 4; r++) o[(size_t)(mm + r) * ldc + nn] = acc[i][j][r] + xr[r];
            } else if (EP == 2) {
                u16* o = (u16*)out;
                float bb = ex1[nn];
#pragma unroll
                for (int r = 0; r < 4; r++) {
                    float v = acc[i][j][r] + bb;
                    o[(size_t)(mm + r) * ldc + nn] = f2bf(0.5f * v * (1.f + erff(v * 0.70710678118654752f)));
                }
            } else {
                float* o = (float*)out;
                float bb = ex1[nn];
#pragma unroll
                for (int r = 0; r < 4; r++) o[(size_t)(mm + r) * ldc + nn] = acc[i][j][r] + bb;
            }
        }
}

// ---------------------------------------------------------------------------
// l2norm sums: norm2[b][col] = sum_n kv[n][col]^2   (col 0..383 = k then v)
// ---------------------------------------------------------------------------
__global__ __launch_bounds__(384) void norm_kernel(const u16* __restrict__ kv,
                                                   float* __restrict__ norm2)
{
    int b = blockIdx.y, ch = blockIdx.x;
    int t = threadIdx.x;
    const u16* base = kv + ((size_t)(b * 4096 + ch * 128)) * 384 + t;
    float s = 0.f;
    for (int r = 0; r < 128; r++) { float v = bf2f(base[(size_t)r * 384]); s += v * v; }
    atomicAdd(&norm2[b * 384 + t], s);
}

// ---------------------------------------------------------------------------
// attention logits partials: raw[b,h,c,d] += sum_{r in chunk} q[r][c]*k[r][d]
// ---------------------------------------------------------------------------
__global__ __launch_bounds__(64) void attnp_kernel(const u16* __restrict__ qt,
                                                   const u16* __restrict__ kvt,
                                                   float* __restrict__ raw)
{
    __shared__ float qT[32 * 69];
    __shared__ float kT[32 * 69];
    int ch = blockIdx.x, h = blockIdx.y, b = blockIdx.z;
    int t = threadIdx.x;
    size_t base = (size_t)(b * 4096 + ch * 64);
    for (int e = t; e < 2048; e += 64) {
        int r = e >> 5, c = e & 31;
        qT[c * 69 + r] = bf2f(qt[(base + r) * 192 + h * 32 + c]);
        kT[c * 69 + r] = bf2f(kvt[(base + r) * 384 + h * 32 + c]);
    }
    __syncthreads();
    int tc = t >> 3, td = t & 7;
    int c0 = tc * 4, d0 = td * 4;
    float acc[4][4] = {};
    for (int r = 0; r < 64; r++) {
        float qv[4], kv4[4];
#pragma unroll
        for (int u = 0; u < 4; u++) { qv[u] = qT[(c0 + u) * 69 + r]; kv4[u] = kT[(d0 + u) * 69 + r]; }
#pragma unroll
        for (int u = 0; u < 4; u++)
#pragma unroll
            for (int v = 0; v < 4; v++) acc[u][v] += qv[u] * kv4[v];
    }
    float* dst = raw + ((size_t)(b * 6 + h)) * 1024;
#pragma unroll
    for (int u = 0; u < 4; u++)
#pragma unroll
        for (int v = 0; v < 4; v++)
            atomicAdd(&dst[(c0 + u) * 32 + d0 + v], acc[u][v]);
}

// ---------------------------------------------------------------------------
// softmax over d with k-norm + temperature folded in; v-norm folded into out
// ---------------------------------------------------------------------------
__global__ __launch_bounds__(1024) void softmax_kernel(const float* __restrict__ raw,
                                                       const float* __restrict__ norm2,
                                                       const float* __restrict__ temp,
                                                       float* __restrict__ att2)
{
    int h = blockIdx.x, b = blockIdx.y;
    int t = threadIdx.x;
    int c = t >> 5, d = t & 31;
    __shared__ float invk[32], invv[32];
    if (t < 32)       invk[t] = 1.f / fmaxf(sqrtf(norm2[b * 384 + h * 32 + t]), 1e-12f);
    else if (t < 64)  invv[t - 32] = 1.f / fmaxf(sqrtf(norm2[b * 384 + 192 + h * 32 + (t - 32)]), 1e-12f);
    __syncthreads();
    float T = temp[h];
    float v = raw[((size_t)(b * 6 + h) * 32 + c) * 32 + d] * invk[d] * T;
    float mx = v;
    for (int s = 16; s > 0; s >>= 1) mx = fmaxf(mx, __shfl_xor(mx, s, 32));
    float e = expf(v - mx);
    float sm = e;
    for (int s = 16; s > 0; s >>= 1) sm += __shfl_xor(sm, s, 32);
    att2[((size_t)(b * 6 + h) * 32 + c) * 32 + d] = (e / sm) * invv[d];
}

// ---------------------------------------------------------------------------
// M_b[b][o2][h*32+d] = sum_c w_proj[o2][h*32+c] * att2[b][h][c][d]  (bf16)
// ---------------------------------------------------------------------------
__global__ __launch_bounds__(192) void mb_kernel(const float* __restrict__ wproj,
                                                 const float* __restrict__ att2,
                                                 u16* __restrict__ Mb)
{
    int o2 = blockIdx.x, b = blockIdx.y, t = threadIdx.x;
    int h = t >> 5, d = t & 31;
    float s = 0.f;
#pragma unroll
    for (int c = 0; c < 32; c++)
        s += wproj[o2 * 192 + h * 32 + c] * att2[((size_t)(b * 6 + h) * 32 + c) * 32 + d];
    Mb[((size_t)b * 192 + o2) * 192 + t] = f2bf(s);
}

// ---------------------------------------------------------------------------
// LN2: xs2 fp32 token-major -> h1 bf16 token-major; one wave per token
// ---------------------------------------------------------------------------
__global__ __launch_bounds__(256) void ln2_kernel(const float* __restrict__ xs2,
                                                  const float* __restrict__ g,
                                                  const float* __restrict__ be,
                                                  u16* __restrict__ h1)
{
    int t = threadIdx.x;
    int wv = t >> 6, l = t & 63;
    size_t m = (size_t)blockIdx.x * 4 + wv;
    const float* row = xs2 + m * 192;
    float v0 = row[l], v1 = row[l + 64], v2 = row[l + 128];
    float s = v0 + v1 + v2, s2 = v0 * v0 + v1 * v1 + v2 * v2;
    for (int sh = 32; sh > 0; sh >>= 1) { s += __shfl_xor(s, sh); s2 += __shfl_xor(s2, sh); }
    float mu = s * (1.f / 192.f);
    float var = s2 * (1.f / 192.f) - mu * mu;
    float rs = rsqrtf(var + 1e-5f);
    u16* o = h1 + m * 192;
    o[l]       = f2bf((v0 - mu) * rs * g[l]       + be[l]);
    o[l + 64]  = f2bf((v1 - mu) * rs * g[l + 64]  + be[l + 64]);
    o[l + 128] = f2bf((v2 - mu) * rs * g[l + 128] + be[l + 128]);
}

// ---------------------------------------------------------------------------
// final: out[b][c][hw] = xs2[m][c] + m2[m][c]  (LDS transpose, coalesced)
// ---------------------------------------------------------------------------
__global__ __launch_bounds__(256) void final_kernel(const float* __restrict__ xs2,
                                                    const float* __restrict__ m2,
                                                    float* __restrict__ out)
{
    __shared__ float tile[192 * 65];
    int blk = blockIdx.x;
    int b = blk >> 6, hw0 = (blk & 63) * 64;
    int t = threadIdx.x;
    size_t mbase = ((size_t)b * 4096 + hw0) * 192;
    for (int i = t; i < 64 * 192; i += 256) {
        int r = i / 192, c = i % 192;
        tile[c * 65 + r] = xs2[mbase + i] + m2[mbase + i];
    }
    __syncthreads();
    for (int i = t; i < 64 * 192; i += 256) {
        int c = i / 64, r = i % 64;
        out[(size_t)b * 786432 + (size_t)c * 4096 + hw0 + r] = tile[c * 65 + r];
    }
}

// ---------------------------------------------------------------------------
extern "C" void kernel_launch(void* const* d_in, const int* in_sizes, int n_in,
                              void* d_out, int out_size, void* d_ws, size_t ws_size,
                              hipStream_t stream)
{
    const float* x      = (const float*)d_in[0];
    const float* gamma1 = (const float*)d_in[1];
    const float* beta1  = (const float*)d_in[2];
    const float* gamma2 = (const float*)d_in[3];
    const float* beta2  = (const float*)d_in[4];
    const float* temp   = (const float*)d_in[5];
    const float* w_qkv  = (const float*)d_in[6];
    const float* w_proj = (const float*)d_in[7];
    const float* w_p    = (const float*)d_in[8];
    const float* b_p    = (const float*)d_in[9];
    const float* w_d    = (const float*)d_in[10];
    const float* w_fc1  = (const float*)d_in[11];
    const float* b_fc1  = (const float*)d_in[12];
    const float* w_fc2  = (const float*)d_in[13];
    const float* b_fc2  = (const float*)d_in[14];
    float* out = (float*)d_out;
    char* ws = (char*)d_ws;

    u16*   xn    = (u16*)(ws + 0);                     // 6.29 MB (aliased: h1)
    float* off   = (float*)(ws + 6291456);             // 1.18 MB
    u16*   adef  = (u16*)(ws + 7471104);               // 56.6 MB (aliased: m1, m2, wpT)
    u16*   wpT   = adef;                               // 110 KB, dead once gather runs
    u16*   m1    = adef;                               // 25.2 MB
    float* m2    = (float*)(ws + 7471104 + 25165824);  // 12.6 MB
    u16*   qt    = (u16*)(ws + 64094208);              // 6.29 MB
    u16*   kvt   = (u16*)(ws + 70385664);              // 12.6 MB
    float* norm2 = (float*)(ws + 82968576);            // 6 KB
    float* araw  = (float*)(ws + 82974720);            // 96 KB
    float* att2  = (float*)(ws + 83073024);            // 96 KB
    u16*   Mb    = (u16*)(ws + 83171328);              // 144 KB
    float* xs2   = (float*)(ws + 83318784);            // 12.6 MB
    u16*   h1    = xn;
    u16*   wdT   = (u16*)(ws + 95901696);
    u16*   wkvT  = (u16*)(ws + 96565248);
    u16*   wf1T  = (u16*)(ws + 96712704);
    u16*   wf2T  = (u16*)(ws + 97007616);              // end 97302528 B

    hipMemsetAsync(norm2, 0, 6144 + 98304, stream);
    prep_kernel<<<1296, 256, 0, stream>>>(w_d, w_qkv, w_fc1, w_fc2, w_p, wdT, wkvT, wf1T, wf2T, wpT);
    ln1_kernel<<<256, 256, 0, stream>>>(x, gamma1, beta1, xn);
    offconv_kernel<<<256, 256, 0, stream>>>(xn, wpT, b_p, off);
    gather_kernel<<<16384, 192, 0, stream>>>(xn, off, adef);
    // deform output conv as GEMM: M=16384 K=1728 N=192
    gemm_bt<32, 192, 32, 96, 0><<<dim3(512, 1), 128, 0, stream>>>(adef, 1728, wdT, 1728, 0, qt, 192, nullptr, 1728);
    // k,v projection: M=16384 K=192 N=384
    gemm_bt<128, 128, 64, 64, 0><<<dim3(128, 3), 256, 0, stream>>>(xn, 192, wkvT, 192, 0, kvt, 384, nullptr, 192);
    norm_kernel<<<dim3(32, 4), 384, 0, stream>>>(kvt, norm2);
    attnp_kernel<<<dim3(64, 6, 4), 64, 0, stream>>>(qt, kvt, araw);
    softmax_kernel<<<dim3(6, 4), 1024, 0, stream>>>(araw, norm2, temp, att2);
    mb_kernel<<<dim3(192, 4), 192, 0, stream>>>(w_proj, att2, Mb);
    // fused attn-apply+proj GEMM on raw v, + x residual -> xs2 fp32
    gemm_bt<32, 192, 32, 96, 1><<<dim3(512, 1), 128, 0, stream>>>(kvt + 192, 384, Mb, 192, 192 * 192, xs2, 192, x, 192);
    ln2_kernel<<<4096, 256, 0, stream>>>(xs2, gamma2, beta2, h1);
    // fc1 + gelu: M=16384 K=192 N=768
    gemm_bt<128, 128, 64, 64, 2><<<dim3(128, 6), 256, 0, stream>>>(h1, 192, wf1T, 192, 0, m1, 768, b_fc1, 192);
    // fc2 + bias: M=16384 K=768 N=192
    gemm_bt<32, 192, 32, 96, 3><<<dim3(512, 1), 128, 0, stream>>>(m1, 768, wf2T, 768, 0, m2, 192, b_fc2, 768);
    final_kernel<<<256, 256, 0, stream>>>(xs2, m2, out);
}

// Round 3
// 288.098 us; speedup vs baseline: 1.7207x; 1.2719x over previous
//
#include <hip/hip_runtime.h>
#include <math.h>

typedef unsigned short u16;
typedef unsigned int u32;
typedef short s16x8 __attribute__((ext_vector_type(8)));
typedef float f32x4 __attribute__((ext_vector_type(4)));

#define AS1 __attribute__((address_space(1)))
#define AS3 __attribute__((address_space(3)))

__device__ __forceinline__ float bf2f(u16 u) {
    union { u32 i; float f; } v; v.i = ((u32)u) << 16; return v.f;
}
__device__ __forceinline__ u16 f2bf(float f) {
    union { float f; u32 i; } v; v.f = f;
    u32 r = v.i + 0x7fffu + ((v.i >> 16) & 1u);
    return (u16)(r >> 16);
}
__device__ __forceinline__ void gll16(const u16* g, u16* l) {
    __builtin_amdgcn_global_load_lds((const AS1 u32*)g, (AS3 u32*)l, 16, 0, 0);
}

// ---------------------------------------------------------------------------
// prep: repack weights to B^T bf16 layouts for the MFMA GEMMs
// ---------------------------------------------------------------------------
__global__ void prep_kernel(const float* __restrict__ wd, const float* __restrict__ wqkv,
                            const float* __restrict__ wfc1, const float* __restrict__ wfc2,
                            const float* __restrict__ wp,
                            u16* __restrict__ wdT, u16* __restrict__ wkvT,
                            u16* __restrict__ wf1T, u16* __restrict__ wf2T,
                            u16* __restrict__ wpT)
{
    int i = blockIdx.x * 256 + threadIdx.x;
    if (i < 331776) {                       // w_dT[o][p*192+c] = w_d[o][c][p]
        int o = i / 1728, r = i % 1728;
        int p = r / 192, c = r % 192;
        wdT[i] = f2bf(wd[(o * 192 + c) * 9 + p]);
    }
    if (i < 73728) {                        // rows C..3C of w_qkv (k,v only)
        int o = i / 192, c = i % 192;
        wkvT[i] = f2bf(wqkv[(192 + o) * 192 + c]);
    }
    if (i < 147456) {
        int n = i / 192, c = i % 192;       // w_fc1 (192,768) -> [768][192]
        wf1T[i] = f2bf(wfc1[c * 768 + n]);
        int n2 = i / 768, hh = i % 768;     // w_fc2 (768,192) -> [192][768]
        wf2T[i] = f2bf(wfc2[hh * 192 + n2]);
    }
    if (i < 31104) {                        // w_pT[n][p*192+c] = w_p[n][c][p], pad to 32 rows
        int n = i / 1728, r = i % 1728;
        int p = r / 192, c = r % 192;
        wpT[i] = f2bf(wp[(n * 192 + c) * 9 + p]);
    } else if (i < 55296) {
        wpT[i] = 0;
    }
}

// ---------------------------------------------------------------------------
// LN1: x NCHW fp32 -> xn token-major bf16 [16384][192]
// ---------------------------------------------------------------------------
__global__ __launch_bounds__(256) void ln1_kernel(const float* __restrict__ x,
                                                  const float* __restrict__ g,
                                                  const float* __restrict__ be,
                                                  u16* __restrict__ xn)
{
    __shared__ float red0[256], red1[256];
    __shared__ float mu_s[64], rs_s[64];
    __shared__ u16 tile[64 * 194];          // stride 194 (97 dwords) = conflict-free
    int t = threadIdx.x, tl = t & 63, cg = t >> 6;
    int m0 = blockIdx.x * 64;
    int b = m0 >> 12, hw0 = m0 & 4095;
    const float* xb = x + (size_t)b * 786432 + hw0 + tl;
    float s = 0.f, s2 = 0.f;
    for (int cc = cg; cc < 192; cc += 4) { float v = xb[cc * 4096]; s += v; s2 += v * v; }
    red0[t] = s; red1[t] = s2;
    __syncthreads();
    if (t < 64) {
        float a = red0[t] + red0[64 + t] + red0[128 + t] + red0[192 + t];
        float q = red1[t] + red1[64 + t] + red1[128 + t] + red1[192 + t];
        float mu = a * (1.f / 192.f);
        float var = q * (1.f / 192.f) - mu * mu;
        mu_s[t] = mu; rs_s[t] = rsqrtf(var + 1e-5f);
    }
    __syncthreads();
    float mu = mu_s[tl], rs = rs_s[tl];
    for (int cc = cg; cc < 192; cc += 4) {
        float v = (xb[cc * 4096] - mu) * rs * g[cc] + be[cc];
        tile[tl * 194 + cc] = f2bf(v);
    }
    __syncthreads();
    u32* dst = (u32*)(xn + (size_t)m0 * 192);
    for (int i = t; i < 64 * 96; i += 256) {
        int r = i / 96, c2 = i % 96;
        dst[i] = *(const u32*)&tile[r * 194 + c2 * 2];
    }
}

// ---------------------------------------------------------------------------
// offset conv as direct MFMA conv: one block per (b,h) row, BM=64 (w axis),
// N=32 (18 padded), K = 9 taps x 192 ch.
// ---------------------------------------------------------------------------
__global__ __launch_bounds__(256) void offconv_kernel(const u16* __restrict__ xn,
                                                      const u16* __restrict__ wpT,
                                                      const float* __restrict__ bp,
                                                      float* __restrict__ off)
{
    __shared__ u16 As[64 * 200];            // stride 200: rows rotate 4 banks
    __shared__ u16 Bs[32 * 200];
    int bh = blockIdx.x;
    int b = bh >> 6, h = bh & 63;
    int t = threadIdx.x;
    int lane = t & 63, wv = t >> 6;
    f32x4 acc[2];
#pragma unroll
    for (int j = 0; j < 2; j++) { acc[j][0] = 0.f; acc[j][1] = 0.f; acc[j][2] = 0.f; acc[j][3] = 0.f; }
    int r = t >> 2, cq = (t & 3) * 48;      // 4 threads per A row, 48 ch each
    for (int p = 0; p < 9; p++) {
        int dh = p / 3 - 1, dw = p % 3 - 1;
        int hr = h + dh, wr = r + dw;
        bool valid = (hr >= 0) && (hr < 64) && (wr >= 0) && (wr < 64);
        const u16* src = xn + ((size_t)(b * 4096 + hr * 64 + wr)) * 192 + cq;
#pragma unroll
        for (int j = 0; j < 6; j++) {
            s16x8 v = {0, 0, 0, 0, 0, 0, 0, 0};
            if (valid) v = *(const s16x8*)(src + j * 8);
            *(s16x8*)&As[r * 200 + cq + j * 8] = v;
        }
#pragma unroll
        for (int i = 0; i < 3; i++) {
            int q = t + i * 256;
            int n = q / 24, c8 = q % 24;
            *(s16x8*)&Bs[n * 200 + c8 * 8] =
                *(const s16x8*)(wpT + n * 1728 + p * 192 + c8 * 8);
        }
        __syncthreads();
#pragma unroll
        for (int kc = 0; kc < 6; kc++) {
            s16x8 af = *(const s16x8*)&As[(wv * 16 + (lane & 15)) * 200 + kc * 32 + (lane >> 4) * 8];
            s16x8 b0 = *(const s16x8*)&Bs[(lane & 15) * 200 + kc * 32 + (lane >> 4) * 8];
            s16x8 b1 = *(const s16x8*)&Bs[(16 + (lane & 15)) * 200 + kc * 32 + (lane >> 4) * 8];
            acc[0] = __builtin_amdgcn_mfma_f32_16x16x32_bf16(af, b0, acc[0], 0, 0, 0);
            acc[1] = __builtin_amdgcn_mfma_f32_16x16x32_bf16(af, b1, acc[1], 0, 0, 0);
        }
        __syncthreads();
    }
    int col = lane & 15;
    int wbase = wv * 16 + (lane >> 4) * 4;
#pragma unroll
    for (int j = 0; j < 2; j++) {
        int n = j * 16 + col;
        if (n < 18) {
            float bb = bp[n];
#pragma unroll
            for (int rr = 0; rr < 4; rr++) {
                int w = wbase + rr;
                off[((size_t)(b * 4096 + h * 64 + w)) * 18 + n] = acc[j][rr] + bb;
            }
        }
    }
}

// ---------------------------------------------------------------------------
// fused bilinear-gather + deform output conv GEMM.
// M-block = 32 tokens, N = 192, K = 9 taps x 192 ch (BK=32, 6 k-steps/tap).
// A-tile is gathered on the fly into LDS (no Adef materialization).
// 4 waves: WN=48 -> TM=2, TN=3.
// ---------------------------------------------------------------------------
__global__ __launch_bounds__(256) void gemm_deform(const u16* __restrict__ xn,
                                                   const float* __restrict__ off,
                                                   const u16* __restrict__ wdT,
                                                   u16* __restrict__ qt)
{
    __shared__ u16 As[32 * 200];            // [token][ch], stride 200 rotates banks
    __shared__ u16 Bs[192 * 32];            // [n-row][BK]
    __shared__ int sidx[32][9][4];
    __shared__ float swt[32][9][4];
    int t = threadIdx.x, lane = t & 63, wv = t >> 6;
    int m0 = blockIdx.x * 32;
    int b = m0 >> 12;
    // --- precompute bilinear corners for 32 tokens x 9 points ---
    for (int i = t; i < 288; i += 256) {
        int mi = i / 9, p = i % 9;
        int m = m0 + mi;
        int hw = m & 4095;
        int h = hw >> 6, w = hw & 63;
        float ox = off[(size_t)m * 18 + p];
        float oy = off[(size_t)m * 18 + 9 + p];
        float px = ox + (float)(h + 1) + (float)(p / 3 - 1);
        float py = oy + (float)(w + 1) + (float)(p % 3 - 1);
        float fx = floorf(px), fy = floorf(py);
        float qlx = fminf(fmaxf(fx, 0.f), 65.f);
        float qly = fminf(fmaxf(fy, 0.f), 65.f);
        float qrx = fminf(fmaxf(fx + 1.f, 0.f), 65.f);
        float qry = fminf(fmaxf(fy + 1.f, 0.f), 65.f);
        float pxc = fminf(fmaxf(px, 0.f), 65.f);
        float pyc = fminf(fmaxf(py, 0.f), 65.f);
        float gxl = 1.f + (qlx - pxc), gxr = 1.f - (qrx - pxc);
        float gyl = 1.f + (qly - pyc), gyr = 1.f - (qry - pyc);
        int xl = (int)qlx, xr = (int)qrx, yl = (int)qly, yr = (int)qry;
        int cx[4] = {xl, xr, xl, xr};
        int cy[4] = {yl, yr, yr, yl};
        float cw[4] = {gxl * gyl, gxr * gyr, gxl * gyr, gxr * gyl};
#pragma unroll
        for (int k = 0; k < 4; k++) {
            bool ok = (cx[k] >= 1) && (cx[k] <= 64) && (cy[k] >= 1) && (cy[k] <= 64);
            sidx[mi][p][k] = ok ? (b * 4096 + (cx[k] - 1) * 64 + (cy[k] - 1)) * 192 : 0;
            swt[mi][p][k] = ok ? cw[k] : 0.f;
        }
    }
    __syncthreads();
    f32x4 acc[2][3];
#pragma unroll
    for (int i = 0; i < 2; i++)
#pragma unroll
        for (int j = 0; j < 3; j++) {
            acc[i][j][0] = 0.f; acc[i][j][1] = 0.f; acc[i][j][2] = 0.f; acc[i][j][3] = 0.f;
        }
    for (int p = 0; p < 9; p++) {
        // --- gather A-tile for this tap: 32 tokens x 192 ch ---
        for (int i = t; i < 768; i += 256) {
            int mi = i / 24, ch = (i % 24) * 8;
            const int*   si = sidx[mi][p];
            const float* sw = swt[mi][p];
            float v[8] = {0.f, 0.f, 0.f, 0.f, 0.f, 0.f, 0.f, 0.f};
#pragma unroll
            for (int k = 0; k < 4; k++) {
                s16x8 cv = *(const s16x8*)(xn + si[k] + ch);
                float wt = sw[k];
#pragma unroll
                for (int j = 0; j < 8; j++) v[j] += wt * bf2f((u16)cv[j]);
            }
            s16x8 ov;
#pragma unroll
            for (int j = 0; j < 8; j++) ov[j] = (short)f2bf(v[j]);
            *(s16x8*)&As[mi * 200 + ch] = ov;
        }
        // --- 6 k-steps of BK=32 against wdT tap slice ---
        for (int kk = 0; kk < 6; kk++) {
#pragma unroll 1
            for (int j = wv; j < 12; j += 4)
                gll16(wdT + (size_t)(j * 16 + (lane >> 2)) * 1728 + p * 192 + kk * 32 + (lane & 3) * 8,
                      Bs + j * 512);
            asm volatile("s_waitcnt vmcnt(0)" ::: "memory");
            __syncthreads();
            s16x8 af[2], bfr[3];
#pragma unroll
            for (int i = 0; i < 2; i++)
                af[i] = *(const s16x8*)&As[(i * 16 + (lane & 15)) * 200 + kk * 32 + (lane >> 4) * 8];
#pragma unroll
            for (int j = 0; j < 3; j++)
                bfr[j] = *(const s16x8*)&Bs[(wv * 48 + j * 16 + (lane & 15)) * 32 + (lane >> 4) * 8];
#pragma unroll
            for (int i = 0; i < 2; i++)
#pragma unroll
                for (int j = 0; j < 3; j++)
                    acc[i][j] = __builtin_amdgcn_mfma_f32_16x16x32_bf16(af[i], bfr[j], acc[i][j], 0, 0, 0);
            __syncthreads();
        }
    }
    int col = lane & 15;
#pragma unroll
    for (int i = 0; i < 2; i++)
#pragma unroll
        for (int j = 0; j < 3; j++) {
            int mm = m0 + i * 16 + (lane >> 4) * 4;
            int nn = wv * 48 + j * 16 + col;
#pragma unroll
            for (int r = 0; r < 4; r++)
                qt[(size_t)(mm + r) * 192 + nn] = f2bf(acc[i][j][r]);
        }
}

// ---------------------------------------------------------------------------
// templated bf16 MFMA GEMM: C[M,N] = A[M,K] * B^T[N,K], m97-style staging
// EP: 0 = bf16 store, 1 = +x residual (NCHW) -> fp32, 2 = +bias,gelu -> bf16,
//     3 = +bias -> fp32
// ---------------------------------------------------------------------------
template<int BM, int BN, int WM, int WN, int EP>
__global__ __launch_bounds__((BM / WM) * (BN / WN) * 64)
void gemm_bt(const u16* __restrict__ A, int lda,
             const u16* __restrict__ B, int ldb, int bstride,
             void* __restrict__ out, int ldc,
             const float* __restrict__ ex1, int K)
{
    constexpr int BK = 32;
    constexpr int WAVES_M = BM / WM, WAVES_N = BN / WN, NW = WAVES_M * WAVES_N;
    constexpr int TM = WM / 16, TN = WN / 16;
    constexpr int NLA = BM / 16, NLB = BN / 16;   // 1KB global_load_lds chunks
    __shared__ u16 As[BM * BK];
    __shared__ u16 Bs[BN * BK];
    int tid = threadIdx.x;
    int lane = tid & 63, wv = tid >> 6;
    int wm = wv % WAVES_M, wn = wv / WAVES_M;
    int m0 = blockIdx.x * BM, n0 = blockIdx.y * BN;
    const u16* Bp = B + (size_t)(m0 >> 12) * bstride;
    f32x4 acc[TM][TN];
#pragma unroll
    for (int i = 0; i < TM; i++)
#pragma unroll
        for (int j = 0; j < TN; j++) {
            acc[i][j][0] = 0.f; acc[i][j][1] = 0.f; acc[i][j][2] = 0.f; acc[i][j][3] = 0.f;
        }
    int arow_l = lane >> 2;
    int acol_l = (lane & 3) * 8;
    for (int k0 = 0; k0 < K; k0 += BK) {
#pragma unroll 1
        for (int j = wv; j < NLA + NLB; j += NW) {
            if (j < NLA) {
                int row = j * 16 + arow_l;
                gll16(A + (size_t)(m0 + row) * lda + k0 + acol_l, As + j * 512);
            } else {
                int row = (j - NLA) * 16 + arow_l;
                gll16(Bp + (size_t)(n0 + row) * ldb + k0 + acol_l, Bs + (j - NLA) * 512);
            }
        }
        asm volatile("s_waitcnt vmcnt(0)" ::: "memory");
        __syncthreads();
        s16x8 af[TM], bfr[TN];
#pragma unroll
        for (int i = 0; i < TM; i++)
            af[i] = *(const s16x8*)&As[(wm * WM + i * 16 + (lane & 15)) * BK + (lane >> 4) * 8];
#pragma unroll
        for (int j = 0; j < TN; j++)
            bfr[j] = *(const s16x8*)&Bs[(wn * WN + j * 16 + (lane & 15)) * BK + (lane >> 4) * 8];
#pragma unroll
        for (int i = 0; i < TM; i++)
#pragma unroll
            for (int j = 0; j < TN; j++)
                acc[i][j] = __builtin_amdgcn_mfma_f32_16x16x32_bf16(af[i], bfr[j], acc[i][j], 0, 0, 0);
        __syncthreads();
    }
    // epilogue: C row = (lane>>4)*4 + r, col = lane&15
    int col = lane & 15;
#pragma unroll
    for (int i = 0; i < TM; i++)
#pragma unroll
        for (int j = 0; j < TN; j++) {
            int mm = m0 + wm * WM + i * 16 + (lane >> 4) * 4;
            int nn = n0 + wn * WN + j * 16 + col;
            if (EP == 0) {
                u16* o = (u16*)out;
#pragma unroll
                for (int r = 0; r < 4; r++) o[(size_t)(mm + r) * ldc + nn] = f2bf(acc[i][j][r]);
            } else if (EP == 1) {
                float* o = (float*)out;
                const float* xr = ex1 + (size_t)(mm >> 12) * 786432 + (size_t)nn * 4096 + (mm & 4095);
#pragma unroll
                for (int r = 0; r < 4; r++) o[(size_t)(mm + r) * ldc + nn] = acc[i][j][r] + xr[r];
            } else if (EP == 2) {
                u16* o = (u16*)out;
                float bb = ex1[nn];
#pragma unroll
                for (int r = 0; r < 4; r++) {
                    float v = acc[i][j][r] + bb;
                    o[(size_t)(mm + r) * ldc + nn] = f2bf(0.5f * v * (1.f + erff(v * 0.70710678118654752f)));
                }
            } else {
                float* o = (float*)out;
                float bb = ex1[nn];
#pragma unroll
                for (int r = 0; r < 4; r++) o[(size_t)(mm + r) * ldc + nn] = acc[i][j][r] + bb;
            }
        }
}

// ---------------------------------------------------------------------------
// l2norm sums: norm2[b][col] = sum_n kv[n][col]^2   (col 0..383 = k then v)
// ---------------------------------------------------------------------------
__global__ __launch_bounds__(384) void norm_kernel(const u16* __restrict__ kv,
                                                   float* __restrict__ norm2)
{
    int b = blockIdx.y, ch = blockIdx.x;
    int t = threadIdx.x;
    const u16* base = kv + ((size_t)(b * 4096 + ch * 128)) * 384 + t;
    float s = 0.f;
    for (int r = 0; r < 128; r++) { float v = bf2f(base[(size_t)r * 384]); s += v * v; }
    atomicAdd(&norm2[b * 384 + t], s);
}

// ---------------------------------------------------------------------------
// attention logits partials: raw[b,h,c,d] += sum_{r in chunk} q[r][c]*k[r][d]
// ---------------------------------------------------------------------------
__global__ __launch_bounds__(64) void attnp_kernel(const u16* __restrict__ qt,
                                                   const u16* __restrict__ kvt,
                                                   float* __restrict__ raw)
{
    __shared__ float qT[32 * 69];
    __shared__ float kT[32 * 69];
    int ch = blockIdx.x, h = blockIdx.y, b = blockIdx.z;
    int t = threadIdx.x;
    size_t base = (size_t)(b * 4096 + ch * 64);
    for (int e = t; e < 2048; e += 64) {
        int r = e >> 5, c = e & 31;
        qT[c * 69 + r] = bf2f(qt[(base + r) * 192 + h * 32 + c]);
        kT[c * 69 + r] = bf2f(kvt[(base + r) * 384 + h * 32 + c]);
    }
    __syncthreads();
    int tc = t >> 3, td = t & 7;
    int c0 = tc * 4, d0 = td * 4;
    float acc[4][4] = {};
    for (int r = 0; r < 64; r++) {
        float qv[4], kv4[4];
#pragma unroll
        for (int u = 0; u < 4; u++) { qv[u] = qT[(c0 + u) * 69 + r]; kv4[u] = kT[(d0 + u) * 69 + r]; }
#pragma unroll
        for (int u = 0; u < 4; u++)
#pragma unroll
            for (int v = 0; v < 4; v++) acc[u][v] += qv[u] * kv4[v];
    }
    float* dst = raw + ((size_t)(b * 6 + h)) * 1024;
#pragma unroll
    for (int u = 0; u < 4; u++)
#pragma unroll
        for (int v = 0; v < 4; v++)
            atomicAdd(&dst[(c0 + u) * 32 + d0 + v], acc[u][v]);
}

// ---------------------------------------------------------------------------
// softmax over d with k-norm + temperature folded in; v-norm folded into out
// ---------------------------------------------------------------------------
__global__ __launch_bounds__(1024) void softmax_kernel(const float* __restrict__ raw,
                                                       const float* __restrict__ norm2,
                                                       const float* __restrict__ temp,
                                                       float* __restrict__ att2)
{
    int h = blockIdx.x, b = blockIdx.y;
    int t = threadIdx.x;
    int c = t >> 5, d = t & 31;
    __shared__ float invk[32], invv[32];
    if (t < 32)       invk[t] = 1.f / fmaxf(sqrtf(norm2[b * 384 + h * 32 + t]), 1e-12f);
    else if (t < 64)  invv[t - 32] = 1.f / fmaxf(sqrtf(norm2[b * 384 + 192 + h * 32 + (t - 32)]), 1e-12f);
    __syncthreads();
    float T = temp[h];
    float v = raw[((size_t)(b * 6 + h) * 32 + c) * 32 + d] * invk[d] * T;
    float mx = v;
    for (int s = 16; s > 0; s >>= 1) mx = fmaxf(mx, __shfl_xor(mx, s, 32));
    float e = expf(v - mx);
    float sm = e;
    for (int s = 16; s > 0; s >>= 1) sm += __shfl_xor(sm, s, 32);
    att2[((size_t)(b * 6 + h) * 32 + c) * 32 + d] = (e / sm) * invv[d];
}

// ---------------------------------------------------------------------------
// M_b[b][o2][h*32+d] = sum_c w_proj[o2][h*32+c] * att2[b][h][c][d]  (bf16)
// ---------------------------------------------------------------------------
__global__ __launch_bounds__(192) void mb_kernel(const float* __restrict__ wproj,
                                                 const float* __restrict__ att2,
                                                 u16* __restrict__ Mb)
{
    int o2 = blockIdx.x, b = blockIdx.y, t = threadIdx.x;
    int h = t >> 5, d = t & 31;
    float s = 0.f;
#pragma unroll
    for (int c = 0; c < 32; c++)
        s += wproj[o2 * 192 + h * 32 + c] * att2[((size_t)(b * 6 + h) * 32 + c) * 32 + d];
    Mb[((size_t)b * 192 + o2) * 192 + t] = f2bf(s);
}

// ---------------------------------------------------------------------------
// LN2: xs2 fp32 token-major -> h1 bf16 token-major; one wave per token
// ---------------------------------------------------------------------------
__global__ __launch_bounds__(256) void ln2_kernel(const float* __restrict__ xs2,
                                                  const float* __restrict__ g,
                                                  const float* __restrict__ be,
                                                  u16* __restrict__ h1)
{
    int t = threadIdx.x;
    int wv = t >> 6, l = t & 63;
    size_t m = (size_t)blockIdx.x * 4 + wv;
    const float* row = xs2 + m * 192;
    float v0 = row[l], v1 = row[l + 64], v2 = row[l + 128];
    float s = v0 + v1 + v2, s2 = v0 * v0 + v1 * v1 + v2 * v2;
    for (int sh = 32; sh > 0; sh >>= 1) { s += __shfl_xor(s, sh); s2 += __shfl_xor(s2, sh); }
    float mu = s * (1.f / 192.f);
    float var = s2 * (1.f / 192.f) - mu * mu;
    float rs = rsqrtf(var + 1e-5f);
    u16* o = h1 + m * 192;
    o[l]       = f2bf((v0 - mu) * rs * g[l]       + be[l]);
    o[l + 64]  = f2bf((v1 - mu) * rs * g[l + 64]  + be[l + 64]);
    o[l + 128] = f2bf((v2 - mu) * rs * g[l + 128] + be[l + 128]);
}

// ---------------------------------------------------------------------------
// final: out[b][c][hw] = xs2[m][c] + m2[m][c]  (LDS transpose, coalesced)
// ---------------------------------------------------------------------------
__global__ __launch_bounds__(256) void final_kernel(const float* __restrict__ xs2,
                                                    const float* __restrict__ m2,
                                                    float* __restrict__ out)
{
    __shared__ float tile[192 * 65];
    int blk = blockIdx.x;
    int b = blk >> 6, hw0 = (blk & 63) * 64;
    int t = threadIdx.x;
    size_t mbase = ((size_t)b * 4096 + hw0) * 192;
    for (int i = t; i < 64 * 192; i += 256) {
        int r = i / 192, c = i % 192;
        tile[c * 65 + r] = xs2[mbase + i] + m2[mbase + i];
    }
    __syncthreads();
    for (int i = t; i < 64 * 192; i += 256) {
        int c = i / 64, r = i % 64;
        out[(size_t)b * 786432 + (size_t)c * 4096 + hw0 + r] = tile[c * 65 + r];
    }
}

// ---------------------------------------------------------------------------
extern "C" void kernel_launch(void* const* d_in, const int* in_sizes, int n_in,
                              void* d_out, int out_size, void* d_ws, size_t ws_size,
                              hipStream_t stream)
{
    const float* x      = (const float*)d_in[0];
    const float* gamma1 = (const float*)d_in[1];
    const float* beta1  = (const float*)d_in[2];
    const float* gamma2 = (const float*)d_in[3];
    const float* beta2  = (const float*)d_in[4];
    const float* temp   = (const float*)d_in[5];
    const float* w_qkv  = (const float*)d_in[6];
    const float* w_proj = (const float*)d_in[7];
    const float* w_p    = (const float*)d_in[8];
    const float* b_p    = (const float*)d_in[9];
    const float* w_d    = (const float*)d_in[10];
    const float* w_fc1  = (const float*)d_in[11];
    const float* b_fc1  = (const float*)d_in[12];
    const float* w_fc2  = (const float*)d_in[13];
    const float* b_fc2  = (const float*)d_in[14];
    float* out = (float*)d_out;
    char* ws = (char*)d_ws;

    u16*   xn    = (u16*)(ws + 0);                     // 6.29 MB (aliased: h1)
    float* off   = (float*)(ws + 6291456);             // 1.18 MB
    u16*   adef  = (u16*)(ws + 7471104);               // region (aliased: m1, wpT)
    u16*   wpT   = adef;                               // 110 KB, dead once offconv runs
    u16*   m1    = adef;                               // 25.2 MB
    float* m2    = (float*)(ws + 7471104 + 25165824);  // 12.6 MB
    u16*   qt    = (u16*)(ws + 64094208);              // 6.29 MB
    u16*   kvt   = (u16*)(ws + 70385664);              // 12.6 MB
    float* norm2 = (float*)(ws + 82968576);            // 6 KB
    float* araw  = (float*)(ws + 82974720);            // 96 KB
    float* att2  = (float*)(ws + 83073024);            // 96 KB
    u16*   Mb    = (u16*)(ws + 83171328);              // 144 KB
    float* xs2   = (float*)(ws + 83318784);            // 12.6 MB
    u16*   h1    = xn;
    u16*   wdT   = (u16*)(ws + 95901696);
    u16*   wkvT  = (u16*)(ws + 96565248);
    u16*   wf1T  = (u16*)(ws + 96712704);
    u16*   wf2T  = (u16*)(ws + 97007616);              // end 97302528 B

    hipMemsetAsync(norm2, 0, 6144 + 98304, stream);
    prep_kernel<<<1296, 256, 0, stream>>>(w_d, w_qkv, w_fc1, w_fc2, w_p, wdT, wkvT, wf1T, wf2T, wpT);
    ln1_kernel<<<256, 256, 0, stream>>>(x, gamma1, beta1, xn);
    offconv_kernel<<<256, 256, 0, stream>>>(xn, wpT, b_p, off);
    // fused gather + deform output conv: M=16384 K=1728 N=192
    gemm_deform<<<512, 256, 0, stream>>>(xn, off, wdT, qt);
    // k,v projection: M=16384 K=192 N=384
    gemm_bt<128, 128, 64, 64, 0><<<dim3(128, 3), 256, 0, stream>>>(xn, 192, wkvT, 192, 0, kvt, 384, nullptr, 192);
    norm_kernel<<<dim3(32, 4), 384, 0, stream>>>(kvt, norm2);
    attnp_kernel<<<dim3(64, 6, 4), 64, 0, stream>>>(qt, kvt, araw);
    softmax_kernel<<<dim3(6, 4), 1024, 0, stream>>>(araw, norm2, temp, att2);
    mb_kernel<<<dim3(192, 4), 192, 0, stream>>>(w_proj, att2, Mb);
    // fused attn-apply+proj GEMM on raw v, + x residual -> xs2 fp32
    gemm_bt<32, 192, 32, 96, 1><<<dim3(512, 1), 128, 0, stream>>>(kvt + 192, 384, Mb, 192, 192 * 192, xs2, 192, x, 192);
    ln2_kernel<<<4096, 256, 0, stream>>>(xs2, gamma2, beta2, h1);
    // fc1 + gelu: M=16384 K=192 N=768
    gemm_bt<128, 128, 64, 64, 2><<<dim3(128, 6), 256, 0, stream>>>(h1, 192, wf1T, 192, 0, m1, 768, b_fc1, 192);
    // fc2 + bias: M=16384 K=768 N=192
    gemm_bt<32, 192, 32, 96, 3><<<dim3(512, 1), 128, 0, stream>>>(m1, 768, wf2T, 768, 0, m2, 192, b_fc2, 768);
    final_kernel<<<256, 256, 0, stream>>>(xs2, m2, out);
}